// Round 4
// baseline (754.514 us; speedup 1.0000x reference)
//
#include <hip/hip_runtime.h>

// BPFingerprint: out[perm(i), :] = [scale0(fp_0[i,:16]), scale1(fp_1[i,:32])]
// where perm is the stable partition (elems==1 rows first, then elems==8).
// Scales constant-folded: sf0 (0,2) -> y = x - 1 ; sf1 (-1,3) -> y = 0.5x - 0.5.
// diff / jacob_0 / jacob_1 / jacob_ind_* are dead inputs (identity fwd).

#define N_ATOMS 50000
#define NB0 16
#define NB1 32
#define NBT 48                       // NB0 + NB1
#define BLK 256
#define N_BLOCKS ((N_ATOMS + BLK - 1) / BLK)   // 196
#define F4_PER_ATOM (NBT / 4)        // 12
#define NWAVES (BLK / 64)            // 4
#define N4 (N_ATOMS / 4)             // 12500 (N_ATOMS % 4 == 0)

__global__ __launch_bounds__(BLK) void bpfp_fused(
    const float* __restrict__ fp0,
    const float* __restrict__ fp1,
    const int*   __restrict__ elems,
    float*       __restrict__ out)
{
    const int b    = blockIdx.x;
    const int t    = threadIdx.x;
    const int lane = t & 63;
    const int wave = t >> 6;
    const int base = b * BLK;        // multiple of 4 -> int4-uniform predicate below

    // ---- Phase 1: H-count before this block + total H, int4-vectorized scan ----
    // elems is 200 KB -> L2-resident across the grid's rescans. Loop iterations
    // are independent; unroll 4 keeps >=4 L2 loads in flight per thread (ILP,
    // since at 196 blocks / 256 CUs there is ~no TLP to hide latency).
    const int4* e4 = (const int4*)elems;
    int before = 0, total = 0;
    #pragma unroll 4
    for (int i = t; i < N4; i += BLK) {
        const int4 e = e4[i];
        const int h = (e.x == 1) + (e.y == 1) + (e.z == 1) + (e.w == 1);
        total  += h;
        before += ((i << 2) < base) ? h : 0;   // all 4 atoms share the predicate
    }
    // wave-level reduce (no barriers), then tiny cross-wave combine
    #pragma unroll
    for (int d = 32; d > 0; d >>= 1) {
        before += __shfl_down(before, d);
        total  += __shfl_down(total, d);
    }
    __shared__ int sB[NWAVES], sT[NWAVES];
    if (lane == 0) { sB[wave] = before; sT[wave] = total; }
    __syncthreads();
    int hOff = 0, nH = 0;
    #pragma unroll
    for (int w = 0; w < NWAVES; ++w) { hOff += sB[w]; nH += sT[w]; }

    // ---- Phase 2: stable intra-block ranks via ballot/popcount ----
    const int i    = base + t;
    const int flag = (i < N_ATOMS) && (elems[i] == 1);
    const unsigned long long bal = __ballot(flag);
    const int waveRank = __popcll(bal & ((1ull << lane) - 1ull));
    __shared__ int wcnt[NWAVES];
    __shared__ int rowOf[BLK];
    if (lane == 0) wcnt[wave] = __popcll(bal);
    __syncthreads();
    int woff = 0;
    #pragma unroll
    for (int w = 0; w < NWAVES; ++w) woff += (w < wave) ? wcnt[w] : 0;
    if (i < N_ATOMS) {
        const int hBefore = hOff + woff + waveRank;       // # H atoms with index < i
        rowOf[t] = flag ? hBefore : (nH + i - hBefore);   // stable partition row
    }
    __syncthreads();

    // ---- Phase 3: coalesced float4 scaled copy (12 float4 per atom) ----
    #pragma unroll
    for (int it = 0; it < F4_PER_ATOM; ++it) {
        const int idx  = it * BLK + t;                // consecutive per lane -> coalesced
        const int aLoc = idx / F4_PER_ATOM;
        const int c    = idx % F4_PER_ATOM;
        const int a    = base + aLoc;
        if (a < N_ATOMS) {
            const int row = rowOf[aLoc];
            float4 v;
            if (c < NB0 / 4) {
                v = ((const float4*)(fp0 + (size_t)a * NB0))[c];
                v.x = v.x - 1.0f; v.y = v.y - 1.0f; v.z = v.z - 1.0f; v.w = v.w - 1.0f;
            } else {
                v = ((const float4*)(fp1 + (size_t)a * NB1))[c - NB0 / 4];
                v.x = 0.5f * v.x - 0.5f; v.y = 0.5f * v.y - 0.5f;
                v.z = 0.5f * v.z - 0.5f; v.w = 0.5f * v.w - 0.5f;
            }
            ((float4*)(out + (size_t)row * NBT))[c] = v;
        }
    }
}

extern "C" void kernel_launch(void* const* d_in, const int* in_sizes, int n_in,
                              void* d_out, int out_size, void* d_ws, size_t ws_size,
                              hipStream_t stream)
{
    // setup_inputs order: 0=diff, 1=fp_0, 2=fp_1, 3=jacob_0, 4=jacob_1,
    //                     5=elems, 6=jacob_ind_0, 7=jacob_ind_1
    const float* fp0   = (const float*)d_in[1];
    const float* fp1   = (const float*)d_in[2];
    const int*   elems = (const int*)  d_in[5];
    float*       out   = (float*)d_out;

    bpfp_fused<<<N_BLOCKS, BLK, 0, stream>>>(fp0, fp1, elems, out);
}